// Round 1
// baseline (615.154 us; speedup 1.0000x reference)
//
#include <hip/hip_runtime.h>
#include <math.h>

#define GRIDP 112
#define NPIX (GRIDP * GRIDP)   // 12544
#define D 16

// Precompute ||v_m||^2 for all vertices.
__global__ __launch_bounds__(256) void v2_kernel(const float* __restrict__ verts,
                                                 float* __restrict__ v2, int M) {
    int m = blockIdx.x * 256 + threadIdx.x;
    if (m >= M) return;
    const float4* r = (const float4*)(verts + (size_t)m * D);
    float4 a = r[0], b = r[1], c = r[2], d = r[3];
    float s = ((a.x*a.x + a.y*a.y) + (a.z*a.z + a.w*a.w))
            + ((b.x*b.x + b.y*b.y) + (b.z*b.z + b.w*b.w))
            + ((c.x*c.x + c.y*c.y) + (c.z*c.z + c.w*c.w))
            + ((d.x*d.x + d.y*d.y) + (d.z*d.z + d.w*d.w));
    v2[m] = s;
}

// Each thread owns one pixel; each block-Y slice owns a chunk of the vertex
// range. score = ||v||^2 - 2*x.v  (the per-pixel ||x||^2 term is constant and
// cannot affect the argmin). Vertex row loads are wave-uniform -> scalar loads.
__global__ __launch_bounds__(256) void argmin_partial(
    const float* __restrict__ feats,   // [B, D, 112, 112]
    const float* __restrict__ verts,   // [M, D]
    const float* __restrict__ v2,      // [M]
    float* __restrict__ pval,          // [S, NPtot]
    int*   __restrict__ pidx,          // [S, NPtot]
    int M, int NPtot, int chunk)
{
    int p = blockIdx.x * 256 + threadIdx.x;   // global pixel id
    if (p >= NPtot) return;
    int b = p / NPIX;
    int n = p - b * NPIX;
    const float* xf = feats + ((size_t)b * D) * NPIX + n;
    float x[D];
#pragma unroll
    for (int d = 0; d < D; ++d) x[d] = xf[(size_t)d * NPIX];

    int s = blockIdx.y;
    int m0 = s * chunk;
    int m1 = m0 + chunk;
    if (m1 > M) m1 = M;

    float best = INFINITY;
    int   bi   = 0;

    for (int m = m0; m < m1; ++m) {
        const float* vr = verts + (size_t)m * D;   // wave-uniform address
        float acc0 = vr[0] * x[0];
        float acc1 = vr[1] * x[1];
        float acc2 = vr[2] * x[2];
        float acc3 = vr[3] * x[3];
#pragma unroll
        for (int d = 4; d < D; d += 4) {
            acc0 = fmaf(vr[d + 0], x[d + 0], acc0);
            acc1 = fmaf(vr[d + 1], x[d + 1], acc1);
            acc2 = fmaf(vr[d + 2], x[d + 2], acc2);
            acc3 = fmaf(vr[d + 3], x[d + 3], acc3);
        }
        float dot   = (acc0 + acc1) + (acc2 + acc3);
        float score = fmaf(-2.0f, dot, v2[m]);
        if (score < best) { best = score; bi = m; }   // strict < : first-occurrence tie-break
    }

    pval[(size_t)s * NPtot + p] = best;
    pidx[(size_t)s * NPtot + p] = bi;
}

// Reduce the S partial minima per pixel; write argmin index as float.
__global__ __launch_bounds__(256) void reduce_kernel(
    const float* __restrict__ pval, const int* __restrict__ pidx,
    float* __restrict__ dps, int S, int NPtot)
{
    int p = blockIdx.x * 256 + threadIdx.x;
    if (p >= NPtot) return;
    float best = pval[p];
    int   bi   = pidx[p];
    for (int s2 = 1; s2 < S; ++s2) {
        float v = pval[(size_t)s2 * NPtot + p];
        int   i = pidx[(size_t)s2 * NPtot + p];
        if (v < best) { best = v; bi = i; }   // earlier chunk wins ties (matches np first-occurrence)
    }
    dps[p] = (float)bi;
}

extern "C" void kernel_launch(void* const* d_in, const int* in_sizes, int n_in,
                              void* d_out, int out_size, void* d_ws, size_t ws_size,
                              hipStream_t stream)
{
    const float* feats = (const float*)d_in[0];
    const float* verts = (const float*)d_in[1];
    int M          = in_sizes[1] / D;          // 27554
    int feat_elems = in_sizes[0];              // 401408
    int B          = feat_elems / (D * NPIX);  // 2
    int NPtot      = B * NPIX;                 // 25088

    float* out = (float*)d_out;

    // Output 0: feats passthrough.
    hipMemcpyAsync(out, feats, (size_t)feat_elems * sizeof(float),
                   hipMemcpyDeviceToDevice, stream);

    // Workspace layout: [v2 : M floats] [pval : S*NPtot floats] [pidx : S*NPtot ints]
    char*  ws  = (char*)d_ws;
    float* v2  = (float*)ws;
    size_t off = (((size_t)M * sizeof(float)) + 255) & ~(size_t)255;
    int S = 16;
    while (S > 1 && off + (size_t)S * NPtot * 8 > ws_size) S >>= 1;
    float* pval = (float*)(ws + off);
    int*   pidx = (int*)(ws + off + (size_t)S * NPtot * sizeof(float));
    int chunk = (M + S - 1) / S;

    v2_kernel<<<dim3((M + 255) / 256), dim3(256), 0, stream>>>(verts, v2, M);

    dim3 grid((NPtot + 255) / 256, S);
    argmin_partial<<<grid, dim3(256), 0, stream>>>(feats, verts, v2, pval, pidx,
                                                   M, NPtot, chunk);

    reduce_kernel<<<dim3((NPtot + 255) / 256), dim3(256), 0, stream>>>(
        pval, pidx, out + feat_elems, S, NPtot);
}

// Round 2
// 598.943 us; speedup vs baseline: 1.0271x; 1.0271x over previous
//
#include <hip/hip_runtime.h>
#include <math.h>

#define GRIDP 112
#define NPIX (GRIDP * GRIDP)   // 12544
#define D 16
#define P 4                    // pixels per thread

// Precompute ||v_m||^2 for all vertices.
__global__ __launch_bounds__(256) void v2_kernel(const float* __restrict__ verts,
                                                 float* __restrict__ v2, int M) {
    int m = blockIdx.x * 256 + threadIdx.x;
    if (m >= M) return;
    const float4* r = (const float4*)(verts + (size_t)m * D);
    float4 a = r[0], b = r[1], c = r[2], d = r[3];
    float s = ((a.x*a.x + a.y*a.y) + (a.z*a.z + a.w*a.w))
            + ((b.x*b.x + b.y*b.y) + (b.z*b.z + b.w*b.w))
            + ((c.x*c.x + c.y*c.y) + (c.z*c.z + c.w*c.w))
            + ((d.x*d.x + d.y*d.y) + (d.z*d.z + d.w*d.w));
    v2[m] = s;
}

// Each thread owns P pixels; blockIdx.y owns a chunk of the vertex range.
// score = ||v||^2 - 2*x.v computed as a single fused chain:
//   acc = v2[m]; acc = fmaf(v_d, (-2x)_d, acc)   (16 FMAs, no combine ops)
// Vertex row loads are wave-uniform -> scalar loads, amortized over P pixels.
__global__ __launch_bounds__(256) void argmin_partial(
    const float* __restrict__ feats,   // [B, D, 112, 112]
    const float* __restrict__ verts,   // [M, D]
    const float* __restrict__ v2,      // [M]
    float* __restrict__ pval,          // [S, NPtot]
    int*   __restrict__ pidx,          // [S, NPtot]
    int M, int NPtot, int chunk)
{
    int tid = threadIdx.x;
    int pbase = blockIdx.x * (256 * P) + tid;   // pixel for k=0; +256 per k

    // Load P pixel vectors, pre-scaled by -2. Clamp OOB pixels to a valid one
    // (stores are guarded) to keep the inner loop divergence-free.
    float xs[P][D];
    int   pp[P];
#pragma unroll
    for (int k = 0; k < P; ++k) {
        int p = pbase + 256 * k;
        pp[k] = p;
        int pc = p < NPtot ? p : NPtot - 1;
        int b  = pc / NPIX;
        int n  = pc - b * NPIX;
        const float* xf = feats + ((size_t)b * D) * NPIX + n;
#pragma unroll
        for (int d = 0; d < D; ++d) xs[k][d] = -2.0f * xf[(size_t)d * NPIX];
    }

    int s  = blockIdx.y;
    int m0 = s * chunk;
    int m1 = m0 + chunk;
    if (m1 > M) m1 = M;

    float best[P];
    int   bi[P];
#pragma unroll
    for (int k = 0; k < P; ++k) { best[k] = INFINITY; bi[k] = 0; }

#pragma unroll 2
    for (int m = m0; m < m1; ++m) {
        const float* vr = verts + (size_t)m * D;   // wave-uniform address
        float base = v2[m];
        float a0 = base, a1 = base, a2 = base, a3 = base;
#pragma unroll
        for (int d = 0; d < D; ++d) {
            float vv = vr[d];
            a0 = fmaf(vv, xs[0][d], a0);
            a1 = fmaf(vv, xs[1][d], a1);
            a2 = fmaf(vv, xs[2][d], a2);
            a3 = fmaf(vv, xs[3][d], a3);
        }
        // strict < : first-occurrence tie-break
        if (a0 < best[0]) { best[0] = a0; bi[0] = m; }
        if (a1 < best[1]) { best[1] = a1; bi[1] = m; }
        if (a2 < best[2]) { best[2] = a2; bi[2] = m; }
        if (a3 < best[3]) { best[3] = a3; bi[3] = m; }
    }

#pragma unroll
    for (int k = 0; k < P; ++k) {
        if (pp[k] < NPtot) {
            pval[(size_t)s * NPtot + pp[k]] = best[k];
            pidx[(size_t)s * NPtot + pp[k]] = bi[k];
        }
    }
}

// Reduce the S partial minima per pixel; write argmin index as float.
__global__ __launch_bounds__(256) void reduce_kernel(
    const float* __restrict__ pval, const int* __restrict__ pidx,
    float* __restrict__ dps, int S, int NPtot)
{
    int p = blockIdx.x * 256 + threadIdx.x;
    if (p >= NPtot) return;
    float best = pval[p];
    int   bi   = pidx[p];
    for (int s2 = 1; s2 < S; ++s2) {
        float v = pval[(size_t)s2 * NPtot + p];
        int   i = pidx[(size_t)s2 * NPtot + p];
        if (v < best) { best = v; bi = i; }   // earlier chunk wins ties
    }
    dps[p] = (float)bi;
}

extern "C" void kernel_launch(void* const* d_in, const int* in_sizes, int n_in,
                              void* d_out, int out_size, void* d_ws, size_t ws_size,
                              hipStream_t stream)
{
    const float* feats = (const float*)d_in[0];
    const float* verts = (const float*)d_in[1];
    int M          = in_sizes[1] / D;          // 27554
    int feat_elems = in_sizes[0];              // 401408
    int B          = feat_elems / (D * NPIX);  // 2
    int NPtot      = B * NPIX;                 // 25088

    float* out = (float*)d_out;

    // Output 0: feats passthrough.
    hipMemcpyAsync(out, feats, (size_t)feat_elems * sizeof(float),
                   hipMemcpyDeviceToDevice, stream);

    // Workspace layout: [v2 : M floats] [pval : S*NPtot floats] [pidx : S*NPtot ints]
    char*  ws  = (char*)d_ws;
    float* v2  = (float*)ws;
    size_t off = (((size_t)M * sizeof(float)) + 255) & ~(size_t)255;
    int S = 32;
    while (S > 1 && off + (size_t)S * NPtot * 8 > ws_size) S >>= 1;
    float* pval = (float*)(ws + off);
    int*   pidx = (int*)(ws + off + (size_t)S * NPtot * sizeof(float));
    int chunk = (M + S - 1) / S;

    v2_kernel<<<dim3((M + 255) / 256), dim3(256), 0, stream>>>(verts, v2, M);

    dim3 grid((NPtot + 256 * P - 1) / (256 * P), S);
    argmin_partial<<<grid, dim3(256), 0, stream>>>(feats, verts, v2, pval, pidx,
                                                   M, NPtot, chunk);

    reduce_kernel<<<dim3((NPtot + 255) / 256), dim3(256), 0, stream>>>(
        pval, pidx, out + feat_elems, S, NPtot);
}

// Round 3
// 190.691 us; speedup vs baseline: 3.2259x; 3.1409x over previous
//
#include <hip/hip_runtime.h>
#include <math.h>
#include <float.h>

#define GRIDP 112
#define NPIX (GRIDP * GRIDP)   // 12544
#define D 16

typedef short s16x8 __attribute__((ext_vector_type(8)));
typedef float f32x16 __attribute__((ext_vector_type(16)));

__device__ inline unsigned short f2bf(float x) {      // RTNE float->bf16 bits
    unsigned u = __float_as_uint(x);
    u += 0x7fffu + ((u >> 16) & 1u);
    return (unsigned short)(u >> 16);
}
__device__ inline float bf2f(unsigned short b) { return __uint_as_float(((unsigned)b) << 16); }

// ---------------- MFMA path ----------------
// Vertices -> A-fragment planes (3 bf16 splits) + v2 table in MFMA C-layout.
// A layout (32x32x16): lane l holds row = l&31, k = 8*(l>>5)+e, e=0..7.
// C layout (verified): col = lane&31, row = (r&3) + 8*(r>>2) + 4*(lane>>5).
__global__ __launch_bounds__(256) void prep_verts(
    const float* __restrict__ verts, unsigned short* __restrict__ afr,
    float* __restrict__ v2t, int M, int Mtiles)
{
    int mp = blockIdx.x * 256 + threadIdx.x;
    if (mp >= Mtiles * 32) return;
    int tile = mp >> 5, row = mp & 31;
    float x[D];
    float v2;
    if (mp < M) {
        const float4* r4 = (const float4*)(verts + (size_t)mp * D);
        float4 a = r4[0], b = r4[1], c = r4[2], d = r4[3];
        x[0]=a.x; x[1]=a.y; x[2]=a.z; x[3]=a.w;
        x[4]=b.x; x[5]=b.y; x[6]=b.z; x[7]=b.w;
        x[8]=c.x; x[9]=c.y; x[10]=c.z; x[11]=c.w;
        x[12]=d.x; x[13]=d.y; x[14]=d.z; x[15]=d.w;
        float s = 0.f;
#pragma unroll
        for (int e = 0; e < D; ++e) s = fmaf(x[e], x[e], s);
        v2 = s;
    } else {
#pragma unroll
        for (int e = 0; e < D; ++e) x[e] = 0.f;
        v2 = FLT_MAX;   // pad vertices never win the argmin
    }
    // v2 table entry for this row: invert row = (r&3)+8*(r>>2)+4h
    int h = (row >> 2) & 1, r = (row & 3) + 4 * (row >> 3);
    v2t[(size_t)(tile * 2 + h) * 16 + r] = v2;

    size_t PSA = (size_t)Mtiles * 512;   // plane stride in ushorts (Mtiles*2*32*8)
#pragma unroll
    for (int e = 0; e < D; ++e) {
        float v = x[e];
        unsigned short t0 = f2bf(v);  float r1 = v - bf2f(t0);
        unsigned short t1 = f2bf(r1); float r2 = r1 - bf2f(t1);
        unsigned short t2 = f2bf(r2);
        int h2 = e >> 3, ee = e & 7;
        size_t o = ((size_t)(tile * 2 + h2) * 32 + row) * 8 + ee;
        afr[o] = t0; afr[o + PSA] = t1; afr[o + 2 * PSA] = t2;
    }
}

// Pixels -> B-fragment planes (3 bf16 splits of -2*x).
// B layout (32x32x16): lane l holds col = l&31, k = 8*(l>>5)+e.
__global__ __launch_bounds__(256) void prep_pixels(
    const float* __restrict__ feats, unsigned short* __restrict__ xfr,
    int NP, int PTiles)
{
    int p = blockIdx.x * 256 + threadIdx.x;
    if (p >= PTiles * 32) return;
    int tile = p >> 5, row = p & 31;
    float x[D];
    if (p < NP) {
        int b = p / NPIX, n = p - b * NPIX;
        const float* xf = feats + ((size_t)b * D) * NPIX + n;
#pragma unroll
        for (int e = 0; e < D; ++e) x[e] = -2.0f * xf[(size_t)e * NPIX];
    } else {
#pragma unroll
        for (int e = 0; e < D; ++e) x[e] = 0.f;
    }
    size_t PSX = (size_t)PTiles * 512;
#pragma unroll
    for (int e = 0; e < D; ++e) {
        float v = x[e];
        unsigned short t0 = f2bf(v);  float r1 = v - bf2f(t0);
        unsigned short t1 = f2bf(r1); float r2 = r1 - bf2f(t1);
        unsigned short t2 = f2bf(r2);
        int h2 = e >> 3, ee = e & 7;
        size_t o = ((size_t)(tile * 2 + h2) * 32 + row) * 8 + ee;
        xfr[o] = t0; xfr[o + PSX] = t1; xfr[o + 2 * PSX] = t2;
    }
}

// One wave per 32-pixel tile; blockIdx.y selects a chunk of 32-vertex tiles.
// Per tile: acc = v2(C-layout) + A_vtx x B_px via 6 split-MFMAs; then per-reg
// running (best, best_tile). Global vertex idx reconstructed in epilogue.
__global__ __launch_bounds__(256) void mfma_argmin(
    const unsigned short* __restrict__ afr, const unsigned short* __restrict__ xfr,
    const float* __restrict__ v2t, float* __restrict__ pval, int* __restrict__ pidx,
    int Mtiles, int chunk, int NP, int PTiles)
{
    int lane = threadIdx.x & 63;
    int pt = blockIdx.x * 4 + (threadIdx.x >> 6);
    if (pt >= PTiles) return;
    int col = lane & 31, h = lane >> 5;

    const s16x8* xb = (const s16x8*)xfr;
    const s16x8* ab = (const s16x8*)afr;
    int PSXu = PTiles * 64;   // plane stride in s16x8 units
    int PSAu = Mtiles * 64;

    int xo = (pt * 2 + h) * 32 + col;
    s16x8 bh = xb[xo], bm = xb[xo + PSXu], bl = xb[xo + 2 * PSXu];

    int mt0 = blockIdx.y * chunk;
    int mt1 = mt0 + chunk; if (mt1 > Mtiles) mt1 = Mtiles;

    float best[16]; int btile[16];
#pragma unroll
    for (int r = 0; r < 16; ++r) { best[r] = FLT_MAX; btile[r] = 0; }

    const s16x8* ap = ab + (size_t)(mt0 * 2 + h) * 32 + col;
    const float* vp = v2t + (size_t)(mt0 * 2 + h) * 16;

#pragma unroll 2
    for (int mt = mt0; mt < mt1; ++mt) {
        s16x8 ah = ap[0], am = ap[PSAu], al = ap[2 * PSAu];
        f32x16 acc = *(const f32x16*)vp;          // ||v||^2 pre-folded as C
        acc = __builtin_amdgcn_mfma_f32_32x32x16_bf16(ah, bh, acc, 0, 0, 0);
        acc = __builtin_amdgcn_mfma_f32_32x32x16_bf16(ah, bm, acc, 0, 0, 0);
        acc = __builtin_amdgcn_mfma_f32_32x32x16_bf16(am, bh, acc, 0, 0, 0);
        acc = __builtin_amdgcn_mfma_f32_32x32x16_bf16(ah, bl, acc, 0, 0, 0);
        acc = __builtin_amdgcn_mfma_f32_32x32x16_bf16(am, bm, acc, 0, 0, 0);
        acc = __builtin_amdgcn_mfma_f32_32x32x16_bf16(al, bh, acc, 0, 0, 0);
#pragma unroll
        for (int r = 0; r < 16; ++r) {
            if (acc[r] < best[r]) { best[r] = acc[r]; btile[r] = mt; }  // strict <: earliest tile wins
        }
        ap += 64;   // 2*32 fragments per tile
        vp += 32;   // 2*16 floats per tile
    }

    // epilogue: reduce 16 slots (tie -> smaller global index), then cross-half
    float bv = FLT_MAX; int bgi = 0x7fffffff;
#pragma unroll
    for (int r = 0; r < 16; ++r) {
        int gi = btile[r] * 32 + ((r & 3) + 8 * (r >> 2)) + 4 * h;
        if (best[r] < bv || (best[r] == bv && gi < bgi)) { bv = best[r]; bgi = gi; }
    }
    float ov = __shfl_xor(bv, 32, 64);
    int  ogi = __shfl_xor(bgi, 32, 64);
    if (ov < bv || (ov == bv && ogi < bgi)) { bv = ov; bgi = ogi; }

    int pixel = pt * 32 + col;
    if (lane < 32 && pixel < NP) {
        int s = blockIdx.y;
        pval[(size_t)s * NP + pixel] = bv;
        pidx[(size_t)s * NP + pixel] = bgi;
    }
}

// Reduce S chunk-partials per pixel (tie -> smaller index); write idx as float.
__global__ __launch_bounds__(256) void reduce_tie(
    const float* __restrict__ pval, const int* __restrict__ pidx,
    float* __restrict__ dps, int S, int NP)
{
    int p = blockIdx.x * 256 + threadIdx.x;
    if (p >= NP) return;
    float bv = pval[p]; int bi = pidx[p];
    for (int s = 1; s < S; ++s) {
        float v = pval[(size_t)s * NP + p];
        int   i = pidx[(size_t)s * NP + p];
        if (v < bv || (v == bv && i < bi)) { bv = v; bi = i; }
    }
    dps[p] = (float)bi;
}

// ---------------- Fallback pure-VALU path (proven in round 2) ----------------
__global__ __launch_bounds__(256) void v2_kernel(const float* __restrict__ verts,
                                                 float* __restrict__ v2, int M) {
    int m = blockIdx.x * 256 + threadIdx.x;
    if (m >= M) return;
    const float4* r = (const float4*)(verts + (size_t)m * D);
    float4 a = r[0], b = r[1], c = r[2], d = r[3];
    v2[m] = ((a.x*a.x + a.y*a.y) + (a.z*a.z + a.w*a.w))
          + ((b.x*b.x + b.y*b.y) + (b.z*b.z + b.w*b.w))
          + ((c.x*c.x + c.y*c.y) + (c.z*c.z + c.w*c.w))
          + ((d.x*d.x + d.y*d.y) + (d.z*d.z + d.w*d.w));
}

__global__ __launch_bounds__(256) void argmin_partial(
    const float* __restrict__ feats, const float* __restrict__ verts,
    const float* __restrict__ v2, float* __restrict__ pval, int* __restrict__ pidx,
    int M, int NPtot, int chunk)
{
    int p = blockIdx.x * 256 + threadIdx.x;
    if (p >= NPtot) return;
    int b = p / NPIX, n = p - b * NPIX;
    const float* xf = feats + ((size_t)b * D) * NPIX + n;
    float x[D];
#pragma unroll
    for (int d2 = 0; d2 < D; ++d2) x[d2] = -2.0f * xf[(size_t)d2 * NPIX];
    int s = blockIdx.y;
    int m0 = s * chunk, m1 = m0 + chunk; if (m1 > M) m1 = M;
    float best = INFINITY; int bi = 0;
    for (int m = m0; m < m1; ++m) {
        const float* vr = verts + (size_t)m * D;
        float acc = v2[m];
#pragma unroll
        for (int d2 = 0; d2 < D; ++d2) acc = fmaf(vr[d2], x[d2], acc);
        if (acc < best) { best = acc; bi = m; }
    }
    pval[(size_t)s * NPtot + p] = best;
    pidx[(size_t)s * NPtot + p] = bi;
}

// ---------------- launch ----------------
extern "C" void kernel_launch(void* const* d_in, const int* in_sizes, int n_in,
                              void* d_out, int out_size, void* d_ws, size_t ws_size,
                              hipStream_t stream)
{
    const float* feats = (const float*)d_in[0];
    const float* verts = (const float*)d_in[1];
    int M          = in_sizes[1] / D;          // 27554
    int feat_elems = in_sizes[0];              // 401408
    int Bn         = feat_elems / (D * NPIX);  // 2
    int NP         = Bn * NPIX;                // 25088
    float* out = (float*)d_out;

    hipMemcpyAsync(out, feats, (size_t)feat_elems * sizeof(float),
                   hipMemcpyDeviceToDevice, stream);

    int PTiles = (NP + 31) >> 5;   // 784
    int Mtiles = (M + 31) >> 5;    // 862

    // workspace layout
    size_t off = 0;
    auto alloc = [&](size_t sz) { size_t o = off; off = (off + sz + 255) & ~(size_t)255; return o; };
    size_t oXF  = alloc((size_t)PTiles * 3072);   // 3 planes * PTiles*2*32*8 * 2B
    size_t oAF  = alloc((size_t)Mtiles * 3072);
    size_t oV2T = alloc((size_t)Mtiles * 128);    // Mtiles*2*16 floats
    size_t base = off;

    int S = 16;
    while (S > 2 && base + (size_t)S * NP * 8 > ws_size) S >>= 1;

    if (base + (size_t)S * NP * 8 <= ws_size) {
        unsigned short* xfr = (unsigned short*)((char*)d_ws + oXF);
        unsigned short* afr = (unsigned short*)((char*)d_ws + oAF);
        float* v2t  = (float*)((char*)d_ws + oV2T);
        float* pval = (float*)((char*)d_ws + base);
        int*   pidx = (int*)((char*)d_ws + base + (size_t)S * NP * 4);

        prep_verts<<<dim3((Mtiles * 32 + 255) / 256), dim3(256), 0, stream>>>(
            verts, afr, v2t, M, Mtiles);
        prep_pixels<<<dim3((PTiles * 32 + 255) / 256), dim3(256), 0, stream>>>(
            feats, xfr, NP, PTiles);

        int chunk = (Mtiles + S - 1) / S;
        mfma_argmin<<<dim3((PTiles + 3) / 4, S), dim3(256), 0, stream>>>(
            afr, xfr, v2t, pval, pidx, Mtiles, chunk, NP, PTiles);

        reduce_tie<<<dim3((NP + 255) / 256), dim3(256), 0, stream>>>(
            pval, pidx, out + feat_elems, S, NP);
    } else {
        // fallback: pure-VALU path
        char* ws = (char*)d_ws;
        float* v2 = (float*)ws;
        size_t o2 = (((size_t)M * 4) + 255) & ~(size_t)255;
        int S2 = 16;
        while (S2 > 1 && o2 + (size_t)S2 * NP * 8 > ws_size) S2 >>= 1;
        float* pval = (float*)(ws + o2);
        int*   pidx = (int*)(ws + o2 + (size_t)S2 * NP * 4);
        int chunk = (M + S2 - 1) / S2;
        v2_kernel<<<dim3((M + 255) / 256), dim3(256), 0, stream>>>(verts, v2, M);
        argmin_partial<<<dim3((NP + 255) / 256, S2), dim3(256), 0, stream>>>(
            feats, verts, v2, pval, pidx, M, NP, chunk);
        reduce_tie<<<dim3((NP + 255) / 256), dim3(256), 0, stream>>>(
            pval, pidx, out + feat_elems, S2, NP);
    }
}